// Round 9
// baseline (303.243 us; speedup 1.0000x reference)
//
#include <hip/hip_runtime.h>
#include <hip/hip_fp16.h>

typedef __attribute__((ext_vector_type(8))) _Float16 half8;
typedef __attribute__((ext_vector_type(4))) float f32x4;
typedef unsigned int u32;

#define ELL_PAD 64
#define NCHUNK 32      // edge chunks; partial arrays = NCHUNK*N*4 = 6.4 MB each
#define RSZ 8192       // hist2: nodes per range (dual 32 KB LDS bins)
#define PRSZ 16384     // place: nodes per range (64 KB LDS cursors)

// ---------- K1: dual LDS histogram (esrc AND edst, zero global atomics) + W pack ----------

__global__ __launch_bounds__(256) void hist2(const int* __restrict__ esrc,
                                             const int* __restrict__ edst,
                                             u32* __restrict__ psrc,
                                             u32* __restrict__ pdst,
                                             const float* __restrict__ Ws,
                                             _Float16* __restrict__ Whi,
                                             _Float16* __restrict__ Wlo,
                                             int E, int N, int chunk, int R,
                                             int histBlocks, int packTotal) {
  __shared__ u32 bs_[RSZ];
  __shared__ u32 bd_[RSZ];
  if (blockIdx.x >= histBlocks) {
    // W pack: B-fragment order for mfma_f32_16x16x32_f16:
    // elem j of (layer,ntile,kstep,lane) = W[k=kstep*32+(lane>>4)*8+j][n=ntile*16+(lane&15)]
    int i = (blockIdx.x - histBlocks) * 256 + threadIdx.x;
    if (i < packTotal) {
      int lane  = i & 63;
      int kstep = (i >> 6) & 3;
      int ntile = (i >> 8) & 7;
      int layer = i >> 11;
      int n  = ntile * 16 + (lane & 15);
      int k0 = kstep * 32 + (lane >> 4) * 8;
      const float* W = Ws + (size_t)layer * 128 * 128;
      size_t base = (size_t)i * 8;
      for (int j = 0; j < 8; j++) {
        float v = W[(k0 + j) * 128 + n];
        _Float16 hi = (_Float16)v;
        Whi[base + j] = hi;
        Wlo[base + j] = (_Float16)(v - (float)hi);   // exact residual
      }
    }
    return;
  }
  int c = blockIdx.x / R;
  int r = blockIdx.x % R;
  int base = r * RSZ;
  int hi = min(RSZ, N - base);
  if (hi <= 0) return;
  for (int j = threadIdx.x; j < RSZ; j += 256) { bs_[j] = 0; bd_[j] = 0; }
  __syncthreads();
  int e0 = c * chunk;
  int e1 = min(E, e0 + chunk);
  for (int i = e0 + threadIdx.x; i < e1; i += 256) {
    unsigned ls = (unsigned)(esrc[i] - base);
    unsigned ld = (unsigned)(edst[i] - base);
    if (ls < (unsigned)RSZ) atomicAdd(&bs_[ls], 1u);
    if (ld < (unsigned)RSZ) atomicAdd(&bd_[ld], 1u);
  }
  __syncthreads();
  u32* ds = psrc + (size_t)c * N + base;
  u32* dd = pdst + (size_t)c * N + base;
  for (int j = threadIdx.x; j < hi; j += 256) { ds[j] = bs_[j]; dd[j] = bd_[j]; }
}

// ---------- K2: per-node reduce (deg_out) + chunk-prefix (exact ELL offsets) ----------
// Register-array version: all NCHUNK loads independent (full MLP), prefix in regs.

__global__ __launch_bounds__(256) void prep(const u32* __restrict__ psrc,
                                            u32* __restrict__ pdst,
                                            int* __restrict__ deg_out,
                                            int* __restrict__ deg_in, int N) {
  int i = blockIdx.x * 256 + threadIdx.x;
  if (i >= N) return;
  u32 s0 = 0, s1 = 0, s2 = 0, s3 = 0;
#pragma unroll
  for (int c = 0; c < NCHUNK; c += 4) {
    s0 += psrc[(size_t)(c + 0) * N + i];
    s1 += psrc[(size_t)(c + 1) * N + i];
    s2 += psrc[(size_t)(c + 2) * N + i];
    s3 += psrc[(size_t)(c + 3) * N + i];
  }
  deg_out[i] = (int)(s0 + s1 + s2 + s3);
  u32 cnt[NCHUNK];
#pragma unroll
  for (int c = 0; c < NCHUNK; c++) cnt[c] = pdst[(size_t)c * N + i];
  u32 run = (u32)i * ELL_PAD;
#pragma unroll
  for (int c = 0; c < NCHUNK; c++) { u32 t = cnt[c]; cnt[c] = run; run += t; }
#pragma unroll
  for (int c = 0; c < NCHUNK; c++) pdst[(size_t)c * N + i] = cnt[c];
  deg_in[i] = (int)(run - (u32)i * ELL_PAD);
}

// ---------- xh[i,:] = fp16( x[i,:] * rsqrt(max(deg_out[i],1)) ) ----------

__global__ __launch_bounds__(256) void xscale(const float* __restrict__ x,
                                              const int* __restrict__ deg_out,
                                              __half2* __restrict__ xh, int n64) {
  int gid = blockIdx.x * 256 + threadIdx.x;
  if (gid >= n64) return;
  int row = gid >> 6;
  int d = deg_out[row]; if (d < 1) d = 1;
  float s = rsqrtf((float)d);
  float2 v = ((const float2*)x)[gid];
  xh[gid] = __floats2half2_rn(v.x * s, v.y * s);
}

// ---------- K3: place edges into ELL — LDS cursors only, zero global atomics ----------

__global__ __launch_bounds__(256) void place(const int* __restrict__ esrc,
                                             const int* __restrict__ edst,
                                             const u32* __restrict__ pdst,
                                             int* __restrict__ ell,
                                             int E, int N, int chunk, int R) {
  __shared__ u32 cur[PRSZ];
  int c = blockIdx.x / R;
  int r = blockIdx.x % R;
  int base = r * PRSZ;
  int hi = min(PRSZ, N - base);
  if (hi <= 0) return;
  for (int j = threadIdx.x; j < hi; j += 256)
    cur[j] = pdst[(size_t)c * N + base + j];
  __syncthreads();
  int e0 = c * chunk;
  int e1 = min(E, e0 + chunk);
  for (int i = e0 + threadIdx.x; i < e1; i += 256) {
    int d = edst[i];
    unsigned loc = (unsigned)(d - base);
    if (loc < (unsigned)hi) {
      u32 p = atomicAdd(&cur[loc], 1u);
      u32 idx = p - (u32)d * ELL_PAD;
      if (idx < ELL_PAD) ell[p] = esrc[i];   // unique position by construction
    }
  }
}

// ---------- SpMM (ELL): row-pair waves ----------
// Each wave handles rows 2p, 2p+1: joint 4+4 loop keeps 8 independent gathers
// in flight for the full common prefix (vs 8/4/1 decay of the single-row batch).

__global__ __launch_bounds__(256) void spmm(const __half2* __restrict__ xh,
                                            const int* __restrict__ deg_in,
                                            const int* __restrict__ ell,
                                            __half2* __restrict__ aggh,
                                            int npair, int n) {
  int pair = blockIdx.x * 4 + (threadIdx.x >> 6);
  if (pair >= npair) return;
  int lane = threadIdx.x & 63;
  int r0 = pair * 2, r1 = r0 + 1;
  int d0 = deg_in[r0];
  int d1 = (r1 < n) ? deg_in[r1] : 0;
  int l0 = d0 > ELL_PAD ? ELL_PAD : d0;
  int l1 = d1 > ELL_PAD ? ELL_PAD : d1;
  const int* ep0 = ell + (size_t)r0 * ELL_PAD;
  const int* ep1 = ell + (size_t)r1 * ELL_PAD;
  float ax0 = 0.f, ay0 = 0.f, ax1 = 0.f, ay1 = 0.f;

  int m = (l0 < l1 ? l0 : l1) & ~3;
  int e = 0;
  for (; e < m; e += 4) {
    int4 ia = *(const int4*)&ep0[e];
    int4 ib = *(const int4*)&ep1[e];
    __half2 a0 = xh[(size_t)ia.x * 64 + lane];
    __half2 a1 = xh[(size_t)ia.y * 64 + lane];
    __half2 a2 = xh[(size_t)ia.z * 64 + lane];
    __half2 a3 = xh[(size_t)ia.w * 64 + lane];
    __half2 b0 = xh[(size_t)ib.x * 64 + lane];
    __half2 b1 = xh[(size_t)ib.y * 64 + lane];
    __half2 b2 = xh[(size_t)ib.z * 64 + lane];
    __half2 b3 = xh[(size_t)ib.w * 64 + lane];
    float2 u0 = __half22float2(a0), u1 = __half22float2(a1);
    float2 u2 = __half22float2(a2), u3 = __half22float2(a3);
    float2 w0 = __half22float2(b0), w1 = __half22float2(b1);
    float2 w2 = __half22float2(b2), w3 = __half22float2(b3);
    ax0 += (u0.x + u1.x) + (u2.x + u3.x);
    ay0 += (u0.y + u1.y) + (u2.y + u3.y);
    ax1 += (w0.x + w1.x) + (w2.x + w3.x);
    ay1 += (w0.y + w1.y) + (w2.y + w3.y);
  }
  // finish row0
  int e0i = e;
  for (; e0i + 4 <= l0; e0i += 4) {
    int4 ia = *(const int4*)&ep0[e0i];
    __half2 a0 = xh[(size_t)ia.x * 64 + lane];
    __half2 a1 = xh[(size_t)ia.y * 64 + lane];
    __half2 a2 = xh[(size_t)ia.z * 64 + lane];
    __half2 a3 = xh[(size_t)ia.w * 64 + lane];
    float2 u0 = __half22float2(a0), u1 = __half22float2(a1);
    float2 u2 = __half22float2(a2), u3 = __half22float2(a3);
    ax0 += (u0.x + u1.x) + (u2.x + u3.x);
    ay0 += (u0.y + u1.y) + (u2.y + u3.y);
  }
  for (; e0i < l0; e0i++) {
    float2 v = __half22float2(xh[(size_t)ep0[e0i] * 64 + lane]);
    ax0 += v.x; ay0 += v.y;
  }
  // finish row1
  int e1i = e;
  for (; e1i + 4 <= l1; e1i += 4) {
    int4 ib = *(const int4*)&ep1[e1i];
    __half2 b0 = xh[(size_t)ib.x * 64 + lane];
    __half2 b1 = xh[(size_t)ib.y * 64 + lane];
    __half2 b2 = xh[(size_t)ib.z * 64 + lane];
    __half2 b3 = xh[(size_t)ib.w * 64 + lane];
    float2 w0 = __half22float2(b0), w1 = __half22float2(b1);
    float2 w2 = __half22float2(b2), w3 = __half22float2(b3);
    ax1 += (w0.x + w1.x) + (w2.x + w3.x);
    ay1 += (w0.y + w1.y) + (w2.y + w3.y);
  }
  for (; e1i < l1; e1i++) {
    float2 v = __half22float2(xh[(size_t)ep1[e1i] * 64 + lane]);
    ax1 += v.x; ay1 += v.y;
  }

  float si0 = rsqrtf((float)(d0 < 1 ? 1 : d0));
  ax0 *= si0; ay0 *= si0;
  aggh[(size_t)r0 * 64 + lane] = __floats2half2_rn(ax0, ay0);
  if (r1 < n) {
    float si1 = rsqrtf((float)(d1 < 1 ? 1 : d1));
    ax1 *= si1; ay1 *= si1;
    aggh[(size_t)r1 * 64 + lane] = __floats2half2_rn(ax1, ay1);
  }
}

// ---------- MFMA GEMM + bias + ReLU (+ rsqrt(deg_out) fold into fp16 output) ----------
// block = 512 (8 waves) -> 128 rows x 128 cols. A = fp16 exact into f16 MFMA;
// W split f16 hi+lo (residual 2^-22).

__global__ __launch_bounds__(512) void gemm_mfma(const _Float16* __restrict__ A,
                                                 const _Float16* __restrict__ Whi,
                                                 const _Float16* __restrict__ Wlo,
                                                 const float* __restrict__ bias,
                                                 const int* __restrict__ deg_out,
                                                 __half* __restrict__ out16,
                                                 float* __restrict__ out32, int n) {
  __shared__ _Float16 Bh[16384];  // 32 KB
  __shared__ _Float16 Bl[16384];  // 32 KB
  {
    uint4* dh = (uint4*)Bh; const uint4* sh = (const uint4*)Whi;
    uint4* dl = (uint4*)Bl; const uint4* sl = (const uint4*)Wlo;
    for (int i = threadIdx.x; i < 2048; i += 512) { dh[i] = sh[i]; dl[i] = sl[i]; }
  }
  __syncthreads();

  const int wave = threadIdx.x >> 6;
  const int lane = threadIdx.x & 63;
  const int quad = lane >> 4;
  const int l16  = lane & 15;
  const int rowBase = blockIdx.x * 128 + wave * 16;
  const size_t arow = (size_t)(rowBase + l16) * 128;

  f32x4 acc[8];
#pragma unroll
  for (int nt = 0; nt < 8; nt++) acc[nt] = (f32x4){0.f, 0.f, 0.f, 0.f};

#pragma unroll
  for (int ks = 0; ks < 4; ks++) {
    half8 a = *(const half8*)&A[arow + ks * 32 + quad * 8];
#pragma unroll
    for (int nt = 0; nt < 8; nt++) {
      int boff = ((nt * 4 + ks) * 64 + lane) * 8;
      half8 bh = *(const half8*)&Bh[boff];
      half8 bl = *(const half8*)&Bl[boff];
      acc[nt] = __builtin_amdgcn_mfma_f32_16x16x32_f16(a, bh, acc[nt], 0, 0, 0);
      acc[nt] = __builtin_amdgcn_mfma_f32_16x16x32_f16(a, bl, acc[nt], 0, 0, 0);
    }
  }

  // C/D: col = lane&15 (+nt*16), row = quad*4 + reg  [m89-verified mapping]
  const int r0 = rowBase + quad * 4;
  float rs[4];
#pragma unroll
  for (int r = 0; r < 4; r++) {
    if (out16 && (r0 + r) < n) {
      int d = deg_out[r0 + r]; if (d < 1) d = 1;
      rs[r] = rsqrtf((float)d);
    } else rs[r] = 1.0f;
  }
#pragma unroll
  for (int nt = 0; nt < 8; nt++) {
    int col = nt * 16 + l16;
    float bv = bias[col];
#pragma unroll
    for (int r = 0; r < 4; r++) {
      int row = r0 + r;
      if (row < n) {
        float v = fmaxf(acc[nt][r] + bv, 0.f);
        if (out16) out16[(size_t)row * 128 + col] = __float2half(v * rs[r]);
        else       out32[(size_t)row * 128 + col] = v;
      }
    }
  }
}

// ---------- launch ----------

extern "C" void kernel_launch(void* const* d_in, const int* in_sizes, int n_in,
                              void* d_out, int out_size, void* d_ws, size_t ws_size,
                              hipStream_t stream) {
  const float* x   = (const float*)d_in[0];
  const float* Ws  = (const float*)d_in[1];
  const float* bs  = (const float*)d_in[2];
  const int* esrc  = (const int*)d_in[3];
  const int* edst  = (const int*)d_in[4];

  const int D = 128;
  const int N = in_sizes[0] / D;
  const int E = in_sizes[3];
  const int L = in_sizes[1] / (D * D);
  const int Npad = ((N + 127) / 128) * 128;
  const int chunk = (E + NCHUNK - 1) / NCHUNK;
  const int R = (N + RSZ - 1) / RSZ;
  const int Rp = (N + PRSZ - 1) / PRSZ;
  const int histBlocks = NCHUNK * R;
  const int packTotal = L * 2048;
  const int packBlocks = (packTotal + 255) / 256;

  // workspace layout, 256B-aligned chunks
  char* base = (char*)d_ws;
  size_t off = 0;
  auto alloc = [&](size_t bytes) {
    char* p = base + off;
    off = (off + bytes + 255) & ~(size_t)255;
    return p;
  };
  int*      deg_out = (int*)alloc((size_t)N * 4);
  int*      deg_in  = (int*)alloc((size_t)N * 4);
  int*      ell     = (int*)alloc((size_t)N * ELL_PAD * 4);
  _Float16* Whi     = (_Float16*)alloc((size_t)L * 16384 * 2);
  _Float16* Wlo     = (_Float16*)alloc((size_t)L * 16384 * 2);
  _Float16* aggh    = (_Float16*)alloc((size_t)Npad * 128 * 2);
  _Float16* xh      = (_Float16*)alloc((size_t)Npad * 128 * 2);
  // Partial histograms alias dead regions (NCHUNK*N*4 = 6.4 MB each):
  //   psrc -> ell   (dead until place writes it, after prep consumed psrc)
  //   pdst -> aggh  (prefix offsets consumed by place; aggh first written by spmm)
  u32*      psrc    = (u32*)ell;
  u32*      pdst    = (u32*)aggh;

  hist2<<<dim3(histBlocks + packBlocks), dim3(256), 0, stream>>>(
      esrc, edst, psrc, pdst, Ws, Whi, Wlo, E, N, chunk, R, histBlocks, packTotal);
  prep<<<dim3((N + 255) / 256), dim3(256), 0, stream>>>(psrc, pdst, deg_out, deg_in, N);
  xscale<<<dim3((N * 64 + 255) / 256), dim3(256), 0, stream>>>(
      x, deg_out, (__half2*)xh, N * 64);
  place<<<dim3(NCHUNK * Rp), dim3(256), 0, stream>>>(
      esrc, edst, pdst, ell, E, N, chunk, Rp);

  float* outf = (float*)d_out;
  const int npair = (N + 1) / 2;
  const dim3 sgrid((npair + 3) / 4), sblk(256);
  const dim3 ggrid(Npad / 128), gblk(512);

  for (int l = 0; l < L; l++) {
    spmm<<<sgrid, sblk, 0, stream>>>((const __half2*)xh, deg_in, ell,
                                     (__half2*)aggh, npair, N);
    bool last = (l == L - 1);
    gemm_mfma<<<ggrid, gblk, 0, stream>>>(aggh,
                                          Whi + (size_t)l * 16384, Wlo + (size_t)l * 16384,
                                          bs + (size_t)l * D, deg_out,
                                          last ? nullptr : (__half*)xh,
                                          last ? outf : nullptr, N);
  }
}

// Round 10
// 272.691 us; speedup vs baseline: 1.1120x; 1.1120x over previous
//
#include <hip/hip_runtime.h>
#include <hip/hip_fp16.h>

typedef __attribute__((ext_vector_type(8))) _Float16 half8;
typedef __attribute__((ext_vector_type(4))) float f32x4;
typedef unsigned int u32;
typedef unsigned short u16;

#define ELL_PAD 64
#define NCHUNK 64      // edge chunks; partial arrays = NCHUNK*N*4 = 12.8 MB each
#define RSZ 8192       // nodes per range (32 KB LDS) for hist2 AND place -> grid 64*7=448

// ---------- K1: dual LDS histogram (esrc AND edst, zero global atomics) + W pack ----------

__global__ __launch_bounds__(256) void hist2(const int* __restrict__ esrc,
                                             const int* __restrict__ edst,
                                             u32* __restrict__ psrc,
                                             u32* __restrict__ pdst,
                                             const float* __restrict__ Ws,
                                             _Float16* __restrict__ Whi,
                                             _Float16* __restrict__ Wlo,
                                             int E, int N, int chunk, int R,
                                             int histBlocks, int packTotal) {
  __shared__ u32 bs_[RSZ];
  __shared__ u32 bd_[RSZ];
  if (blockIdx.x >= histBlocks) {
    // W pack: B-fragment order for mfma_f32_16x16x32_f16:
    // elem j of (layer,ntile,kstep,lane) = W[k=kstep*32+(lane>>4)*8+j][n=ntile*16+(lane&15)]
    int i = (blockIdx.x - histBlocks) * 256 + threadIdx.x;
    if (i < packTotal) {
      int lane  = i & 63;
      int kstep = (i >> 6) & 3;
      int ntile = (i >> 8) & 7;
      int layer = i >> 11;
      int n  = ntile * 16 + (lane & 15);
      int k0 = kstep * 32 + (lane >> 4) * 8;
      const float* W = Ws + (size_t)layer * 128 * 128;
      size_t base = (size_t)i * 8;
      for (int j = 0; j < 8; j++) {
        float v = W[(k0 + j) * 128 + n];
        _Float16 hi = (_Float16)v;
        Whi[base + j] = hi;
        Wlo[base + j] = (_Float16)(v - (float)hi);   // exact residual
      }
    }
    return;
  }
  int c = blockIdx.x / R;
  int r = blockIdx.x % R;
  int base = r * RSZ;
  int hi = min(RSZ, N - base);
  if (hi <= 0) return;
  for (int j = threadIdx.x; j < RSZ; j += 256) { bs_[j] = 0; bd_[j] = 0; }
  __syncthreads();
  int e0 = c * chunk;
  int e1 = min(E, e0 + chunk);
  for (int i = e0 + threadIdx.x; i < e1; i += 256) {
    unsigned ls = (unsigned)(esrc[i] - base);
    unsigned ld = (unsigned)(edst[i] - base);
    if (ls < (unsigned)RSZ) atomicAdd(&bs_[ls], 1u);
    if (ld < (unsigned)RSZ) atomicAdd(&bd_[ld], 1u);
  }
  __syncthreads();
  u32* ds = psrc + (size_t)c * N + base;
  u32* dd = pdst + (size_t)c * N + base;
  for (int j = threadIdx.x; j < hi; j += 256) { ds[j] = bs_[j]; dd[j] = bd_[j]; }
}

// ---------- K2: per-node reduce (deg_out) + chunk-prefix (exact ELL offsets) ----------
// Register-array version: all NCHUNK loads independent (full MLP), prefix in regs.

__global__ __launch_bounds__(256) void prep(const u32* __restrict__ psrc,
                                            u32* __restrict__ pdst,
                                            int* __restrict__ deg_out,
                                            int* __restrict__ deg_in, int N) {
  int i = blockIdx.x * 256 + threadIdx.x;
  if (i >= N) return;
  u32 s0 = 0, s1 = 0, s2 = 0, s3 = 0;
#pragma unroll
  for (int c = 0; c < NCHUNK; c += 4) {
    s0 += psrc[(size_t)(c + 0) * N + i];
    s1 += psrc[(size_t)(c + 1) * N + i];
    s2 += psrc[(size_t)(c + 2) * N + i];
    s3 += psrc[(size_t)(c + 3) * N + i];
  }
  deg_out[i] = (int)(s0 + s1 + s2 + s3);
  u32 cnt[NCHUNK];
#pragma unroll
  for (int c = 0; c < NCHUNK; c++) cnt[c] = pdst[(size_t)c * N + i];
  u32 run = (u32)i * ELL_PAD;
#pragma unroll
  for (int c = 0; c < NCHUNK; c++) { u32 t = cnt[c]; cnt[c] = run; run += t; }
#pragma unroll
  for (int c = 0; c < NCHUNK; c++) pdst[(size_t)c * N + i] = cnt[c];
  deg_in[i] = (int)(run - (u32)i * ELL_PAD);
}

// ---------- xh[i,:] = fp16( x[i,:] * rsqrt(max(deg_out[i],1)) ) ----------

__global__ __launch_bounds__(256) void xscale(const float* __restrict__ x,
                                              const int* __restrict__ deg_out,
                                              __half2* __restrict__ xh, int n64) {
  int gid = blockIdx.x * 256 + threadIdx.x;
  if (gid >= n64) return;
  int row = gid >> 6;
  int d = deg_out[row]; if (d < 1) d = 1;
  float s = rsqrtf((float)d);
  float2 v = ((const float2*)x)[gid];
  xh[gid] = __floats2half2_rn(v.x * s, v.y * s);
}

// ---------- K3: place edges into ELL (u16 src ids) — LDS cursors, zero global atomics ----------

__global__ __launch_bounds__(256) void place(const int* __restrict__ esrc,
                                             const int* __restrict__ edst,
                                             const u32* __restrict__ pdst,
                                             u16* __restrict__ ell,
                                             int E, int N, int chunk, int R) {
  __shared__ u32 cur[RSZ];
  int c = blockIdx.x / R;
  int r = blockIdx.x % R;
  int base = r * RSZ;
  int hi = min(RSZ, N - base);
  if (hi <= 0) return;
  for (int j = threadIdx.x; j < hi; j += 256)
    cur[j] = pdst[(size_t)c * N + base + j];
  __syncthreads();
  int e0 = c * chunk;
  int e1 = min(E, e0 + chunk);
  for (int i = e0 + threadIdx.x; i < e1; i += 256) {
    int d = edst[i];
    unsigned loc = (unsigned)(d - base);
    if (loc < (unsigned)hi) {
      u32 p = atomicAdd(&cur[loc], 1u);
      u32 idx = p - (u32)d * ELL_PAD;
      if (idx < ELL_PAD) ell[p] = (u16)esrc[i];   // unique position by construction
    }
  }
}

// ---------- SpMM (ELL): row-pair waves, u16 indices ----------
// Each wave handles rows 2p, 2p+1: joint 4+4 loop keeps 8 independent gathers
// in flight over the common prefix; ushort4 index loads (8B, wave-uniform rows).

__global__ __launch_bounds__(256) void spmm(const __half2* __restrict__ xh,
                                            const int* __restrict__ deg_in,
                                            const u16* __restrict__ ell,
                                            __half2* __restrict__ aggh,
                                            int npair, int n) {
  int pair = blockIdx.x * 4 + (threadIdx.x >> 6);
  if (pair >= npair) return;
  int lane = threadIdx.x & 63;
  int r0 = pair * 2, r1 = r0 + 1;
  int d0 = deg_in[r0];
  int d1 = (r1 < n) ? deg_in[r1] : 0;
  int l0 = d0 > ELL_PAD ? ELL_PAD : d0;
  int l1 = d1 > ELL_PAD ? ELL_PAD : d1;
  const u16* ep0 = ell + (size_t)r0 * ELL_PAD;
  const u16* ep1 = ell + (size_t)r1 * ELL_PAD;
  float ax0 = 0.f, ay0 = 0.f, ax1 = 0.f, ay1 = 0.f;

  int m = (l0 < l1 ? l0 : l1) & ~3;
  int e = 0;
  for (; e < m; e += 4) {
    ushort4 ia = *(const ushort4*)&ep0[e];
    ushort4 ib = *(const ushort4*)&ep1[e];
    __half2 a0 = xh[(size_t)ia.x * 64 + lane];
    __half2 a1 = xh[(size_t)ia.y * 64 + lane];
    __half2 a2 = xh[(size_t)ia.z * 64 + lane];
    __half2 a3 = xh[(size_t)ia.w * 64 + lane];
    __half2 b0 = xh[(size_t)ib.x * 64 + lane];
    __half2 b1 = xh[(size_t)ib.y * 64 + lane];
    __half2 b2 = xh[(size_t)ib.z * 64 + lane];
    __half2 b3 = xh[(size_t)ib.w * 64 + lane];
    float2 u0 = __half22float2(a0), u1 = __half22float2(a1);
    float2 u2 = __half22float2(a2), u3 = __half22float2(a3);
    float2 w0 = __half22float2(b0), w1 = __half22float2(b1);
    float2 w2 = __half22float2(b2), w3 = __half22float2(b3);
    ax0 += (u0.x + u1.x) + (u2.x + u3.x);
    ay0 += (u0.y + u1.y) + (u2.y + u3.y);
    ax1 += (w0.x + w1.x) + (w2.x + w3.x);
    ay1 += (w0.y + w1.y) + (w2.y + w3.y);
  }
  // finish row0
  int e0i = e;
  for (; e0i + 4 <= l0; e0i += 4) {
    ushort4 ia = *(const ushort4*)&ep0[e0i];
    __half2 a0 = xh[(size_t)ia.x * 64 + lane];
    __half2 a1 = xh[(size_t)ia.y * 64 + lane];
    __half2 a2 = xh[(size_t)ia.z * 64 + lane];
    __half2 a3 = xh[(size_t)ia.w * 64 + lane];
    float2 u0 = __half22float2(a0), u1 = __half22float2(a1);
    float2 u2 = __half22float2(a2), u3 = __half22float2(a3);
    ax0 += (u0.x + u1.x) + (u2.x + u3.x);
    ay0 += (u0.y + u1.y) + (u2.y + u3.y);
  }
  for (; e0i < l0; e0i++) {
    float2 v = __half22float2(xh[(size_t)ep0[e0i] * 64 + lane]);
    ax0 += v.x; ay0 += v.y;
  }
  // finish row1
  int e1i = e;
  for (; e1i + 4 <= l1; e1i += 4) {
    ushort4 ib = *(const ushort4*)&ep1[e1i];
    __half2 b0 = xh[(size_t)ib.x * 64 + lane];
    __half2 b1 = xh[(size_t)ib.y * 64 + lane];
    __half2 b2 = xh[(size_t)ib.z * 64 + lane];
    __half2 b3 = xh[(size_t)ib.w * 64 + lane];
    float2 w0 = __half22float2(b0), w1 = __half22float2(b1);
    float2 w2 = __half22float2(b2), w3 = __half22float2(b3);
    ax1 += (w0.x + w1.x) + (w2.x + w3.x);
    ay1 += (w0.y + w1.y) + (w2.y + w3.y);
  }
  for (; e1i < l1; e1i++) {
    float2 v = __half22float2(xh[(size_t)ep1[e1i] * 64 + lane]);
    ax1 += v.x; ay1 += v.y;
  }

  float si0 = rsqrtf((float)(d0 < 1 ? 1 : d0));
  ax0 *= si0; ay0 *= si0;
  aggh[(size_t)r0 * 64 + lane] = __floats2half2_rn(ax0, ay0);
  if (r1 < n) {
    float si1 = rsqrtf((float)(d1 < 1 ? 1 : d1));
    ax1 *= si1; ay1 *= si1;
    aggh[(size_t)r1 * 64 + lane] = __floats2half2_rn(ax1, ay1);
  }
}

// ---------- MFMA GEMM + bias + ReLU (+ rsqrt(deg_out) fold into fp16 output) ----------
// block = 512 (8 waves) -> 128 rows x 128 cols. A = fp16 exact into f16 MFMA;
// W split f16 hi+lo (residual 2^-22).

__global__ __launch_bounds__(512) void gemm_mfma(const _Float16* __restrict__ A,
                                                 const _Float16* __restrict__ Whi,
                                                 const _Float16* __restrict__ Wlo,
                                                 const float* __restrict__ bias,
                                                 const int* __restrict__ deg_out,
                                                 __half* __restrict__ out16,
                                                 float* __restrict__ out32, int n) {
  __shared__ _Float16 Bh[16384];  // 32 KB
  __shared__ _Float16 Bl[16384];  // 32 KB
  {
    uint4* dh = (uint4*)Bh; const uint4* sh = (const uint4*)Whi;
    uint4* dl = (uint4*)Bl; const uint4* sl = (const uint4*)Wlo;
    for (int i = threadIdx.x; i < 2048; i += 512) { dh[i] = sh[i]; dl[i] = sl[i]; }
  }
  __syncthreads();

  const int wave = threadIdx.x >> 6;
  const int lane = threadIdx.x & 63;
  const int quad = lane >> 4;
  const int l16  = lane & 15;
  const int rowBase = blockIdx.x * 128 + wave * 16;
  const size_t arow = (size_t)(rowBase + l16) * 128;

  f32x4 acc[8];
#pragma unroll
  for (int nt = 0; nt < 8; nt++) acc[nt] = (f32x4){0.f, 0.f, 0.f, 0.f};

#pragma unroll
  for (int ks = 0; ks < 4; ks++) {
    half8 a = *(const half8*)&A[arow + ks * 32 + quad * 8];
#pragma unroll
    for (int nt = 0; nt < 8; nt++) {
      int boff = ((nt * 4 + ks) * 64 + lane) * 8;
      half8 bh = *(const half8*)&Bh[boff];
      half8 bl = *(const half8*)&Bl[boff];
      acc[nt] = __builtin_amdgcn_mfma_f32_16x16x32_f16(a, bh, acc[nt], 0, 0, 0);
      acc[nt] = __builtin_amdgcn_mfma_f32_16x16x32_f16(a, bl, acc[nt], 0, 0, 0);
    }
  }

  // C/D: col = lane&15 (+nt*16), row = quad*4 + reg  [m89-verified mapping]
  const int r0 = rowBase + quad * 4;
  float rs[4];
#pragma unroll
  for (int r = 0; r < 4; r++) {
    if (out16 && (r0 + r) < n) {
      int d = deg_out[r0 + r]; if (d < 1) d = 1;
      rs[r] = rsqrtf((float)d);
    } else rs[r] = 1.0f;
  }
#pragma unroll
  for (int nt = 0; nt < 8; nt++) {
    int col = nt * 16 + l16;
    float bv = bias[col];
#pragma unroll
    for (int r = 0; r < 4; r++) {
      int row = r0 + r;
      if (row < n) {
        float v = fmaxf(acc[nt][r] + bv, 0.f);
        if (out16) out16[(size_t)row * 128 + col] = __float2half(v * rs[r]);
        else       out32[(size_t)row * 128 + col] = v;
      }
    }
  }
}

// ---------- launch ----------

extern "C" void kernel_launch(void* const* d_in, const int* in_sizes, int n_in,
                              void* d_out, int out_size, void* d_ws, size_t ws_size,
                              hipStream_t stream) {
  const float* x   = (const float*)d_in[0];
  const float* Ws  = (const float*)d_in[1];
  const float* bs  = (const float*)d_in[2];
  const int* esrc  = (const int*)d_in[3];
  const int* edst  = (const int*)d_in[4];

  const int D = 128;
  const int N = in_sizes[0] / D;
  const int E = in_sizes[3];
  const int L = in_sizes[1] / (D * D);
  const int Npad = ((N + 127) / 128) * 128;
  const int chunk = (E + NCHUNK - 1) / NCHUNK;
  const int R = (N + RSZ - 1) / RSZ;
  const int histBlocks = NCHUNK * R;
  const int packTotal = L * 2048;
  const int packBlocks = (packTotal + 255) / 256;

  // workspace layout, 256B-aligned chunks (no aliasing; ws ~256 MB, we use ~58 MB)
  char* base = (char*)d_ws;
  size_t off = 0;
  auto alloc = [&](size_t bytes) {
    char* p = base + off;
    off = (off + bytes + 255) & ~(size_t)255;
    return p;
  };
  int*      deg_out = (int*)alloc((size_t)N * 4);
  int*      deg_in  = (int*)alloc((size_t)N * 4);
  u16*      ell     = (u16*)alloc((size_t)N * ELL_PAD * 2);
  _Float16* Whi     = (_Float16*)alloc((size_t)L * 16384 * 2);
  _Float16* Wlo     = (_Float16*)alloc((size_t)L * 16384 * 2);
  _Float16* aggh    = (_Float16*)alloc((size_t)Npad * 128 * 2);
  _Float16* xh      = (_Float16*)alloc((size_t)Npad * 128 * 2);
  u32*      psrc    = (u32*)alloc((size_t)NCHUNK * N * 4);
  u32*      pdst    = (u32*)alloc((size_t)NCHUNK * N * 4);

  hist2<<<dim3(histBlocks + packBlocks), dim3(256), 0, stream>>>(
      esrc, edst, psrc, pdst, Ws, Whi, Wlo, E, N, chunk, R, histBlocks, packTotal);
  prep<<<dim3((N + 255) / 256), dim3(256), 0, stream>>>(psrc, pdst, deg_out, deg_in, N);
  xscale<<<dim3((N * 64 + 255) / 256), dim3(256), 0, stream>>>(
      x, deg_out, (__half2*)xh, N * 64);
  place<<<dim3(histBlocks), dim3(256), 0, stream>>>(
      esrc, edst, pdst, ell, E, N, chunk, R);

  float* outf = (float*)d_out;
  const int npair = (N + 1) / 2;
  const dim3 sgrid((npair + 3) / 4), sblk(256);
  const dim3 ggrid(Npad / 128), gblk(512);

  for (int l = 0; l < L; l++) {
    spmm<<<sgrid, sblk, 0, stream>>>((const __half2*)xh, deg_in, ell,
                                     (__half2*)aggh, npair, N);
    bool last = (l == L - 1);
    gemm_mfma<<<ggrid, gblk, 0, stream>>>(aggh,
                                          Whi + (size_t)l * 16384, Wlo + (size_t)l * 16384,
                                          bs + (size_t)l * D, deg_out,
                                          last ? nullptr : (__half*)xh,
                                          last ? outf : nullptr, N);
  }
}